// Round 4
// baseline (580.418 us; speedup 1.0000x reference)
//
#include <hip/hip_runtime.h>
#include <hip/hip_bf16.h>
#include <stdint.h>
#include <math.h>

#define B_ 128
#define P_ 256
#define H_ 512
#define HEADS_ 8
#define HD_ 64
#define RANK_ 32
#define PH_ (P_*H_)        // 131072
#define TAU_ 0.3f
#define ALPHA_ 0.9f
#define EPS_ 1e-5f
#define BPP_ (B_*P_*P_)    // 8388608
#define N2_ (2*P_*RANK_)   // 16384
#define KCH_ 128           // split-K chunks for gemm0 (each 1024 k)

typedef __attribute__((ext_vector_type(4))) float floatx4;
typedef __attribute__((ext_vector_type(8))) short shortx8;

__device__ inline float wsum64(float v){
  #pragma unroll
  for (int m=32;m>0;m>>=1) v += __shfl_xor(v, m, 64);
  return v;
}
// DPP full-wave sum: result valid in lane 63 (VALU-rate, no LDS pipe)
__device__ inline float dpp_sum(float v){
  union{float f; int i;} u, t;
  u.f = v;
  t.i = __builtin_amdgcn_update_dpp(0, u.i, 0x111, 0xf, 0xf, true); u.f += t.f; // row_shr:1
  t.i = __builtin_amdgcn_update_dpp(0, u.i, 0x112, 0xf, 0xf, true); u.f += t.f; // row_shr:2
  t.i = __builtin_amdgcn_update_dpp(0, u.i, 0x114, 0xf, 0xf, true); u.f += t.f; // row_shr:4
  t.i = __builtin_amdgcn_update_dpp(0, u.i, 0x118, 0xf, 0xf, true); u.f += t.f; // row_shr:8
  t.i = __builtin_amdgcn_update_dpp(0, u.i, 0x142, 0xf, 0xf, true); u.f += t.f; // row_bcast:15
  t.i = __builtin_amdgcn_update_dpp(0, u.i, 0x143, 0xf, 0xf, true); u.f += t.f; // row_bcast:31
  return u.f;
}
__device__ inline unsigned short f2bf(float f){
  union{float f; uint32_t u;} a; a.f=f;
  uint32_t r = (a.u + 0x7fffu + ((a.u>>16)&1u))>>16;
  return (unsigned short)r;
}
// 8x f32 -> 8x bf16 via 4x v_cvt_pk_bf16_f32 (RNE, bit-identical to f2bf, 4 instr vs ~24)
__device__ inline shortx8 pack_bf16x8(floatx4 a, floatx4 b){
  union{ unsigned int u[4]; shortx8 s; } r;
  asm("v_cvt_pk_bf16_f32 %0, %1, %2" : "=v"(r.u[0]) : "v"(a.x), "v"(a.y));
  asm("v_cvt_pk_bf16_f32 %0, %1, %2" : "=v"(r.u[1]) : "v"(a.z), "v"(a.w));
  asm("v_cvt_pk_bf16_f32 %0, %1, %2" : "=v"(r.u[2]) : "v"(b.x), "v"(b.y));
  asm("v_cvt_pk_bf16_f32 %0, %1, %2" : "=v"(r.u[3]) : "v"(b.z), "v"(b.w));
  return r.s;
}
#define GLL16(gp, lp) __builtin_amdgcn_global_load_lds( \
    (const __attribute__((address_space(1))) unsigned int*)(gp), \
    (__attribute__((address_space(3))) unsigned int*)(lp), 16, 0, 0)

// ---------------- k1: head constants (block 0) + res = x@res_w^T+res_b (blocks 1..128) --------
__global__ void k_setup_res(const float* qw, const float* qb, const float* kw, const float* kb,
                        const float* vw, const float* vb,
                        const float* x, const float* rw, const float* rb,
                        float* HC, float* wvh, float* cvh, float* res){
  if(blockIdx.x == 0){
    int lane = threadIdx.x & 63, h = threadIdx.x >> 6;
    int j = h*64 + lane;
    float qwv=qw[j], qbv=qb[j], kwv=kw[j], kbv=kb[j], vwv=vw[j], vbv=vb[j];
    const float inv64 = 1.0f/64.0f;
    float mqw = wsum64(qwv)*inv64, mqb = wsum64(qbv)*inv64;
    float mkw = wsum64(kwv)*inv64, mkb = wsum64(kbv)*inv64;
    float mvw = wsum64(vwv)*inv64, mvb = wsum64(vbv)*inv64;
    float aq=qwv-mqw, cq=qbv-mqb, ak=kwv-mkw, ck=kbv-mkb, av=vwv-mvw, cv=vbv-mvb;
    float Aq=wsum64(aq*aq), Bq=wsum64(aq*cq), Cq=wsum64(cq*cq);
    float Ak=wsum64(ak*ak), Bk=wsum64(ak*ck), Ck=wsum64(ck*ck);
    float Av=wsum64(av*av), Bv=wsum64(av*cv), Cv=wsum64(cv*cv);
    float Dww=wsum64(aq*ak), Dwc=wsum64(aq*ck), Dcw=wsum64(cq*ak), Dcc=wsum64(cq*ck);
    wvh[j]=av; cvh[j]=cv;
    if(lane==0){
      float* o = HC + h*16;
      o[0]=Aq;o[1]=Bq;o[2]=Cq;o[3]=Ak;o[4]=Bk;o[5]=Ck;o[6]=Av;o[7]=Bv;o[8]=Cv;
      o[9]=Dww;o[10]=Dwc;o[11]=Dcw;o[12]=Dcc;
    }
  } else {
    __shared__ float xs[P_];
    int b = blockIdx.x - 1, n = threadIdx.x;
    if(n < P_) xs[n] = x[b*P_ + n];
    __syncthreads();
    float acc = rb[n];
    const float* w = rw + (size_t)n*P_;
    #pragma unroll 4
    for(int p=0;p<P_;p+=4){
      floatx4 wv = *(const floatx4*)(w+p);
      acc += xs[p]*wv.x + xs[p+1]*wv.y + xs[p+2]*wv.z + xs[p+3]*wv.w;
    }
    res[b*H_ + n] = acc;
  }
}

// ---------------- k2: attention + fused h-assembly/LayerNorm/z-write -------------------------
__global__ __launch_bounds__(256) void k_attn(const float* x, const float* HCg,
        const float* res, const float* wvh, const float* cvh,
        const float* lng, const float* lnb,
        unsigned short* z, float* am_out){
  __shared__ float xs[P_];
  __shared__ float hcs[HEADS_*16];
  __shared__ float big[HEADS_*P_*4];     // t1t|t2t|u1t|u2t during head loop; overlay after
  __shared__ float s1s[HEADS_*32], s2s[HEADS_*32];
  float* t1t = big;
  float* t2t = big + HEADS_*P_;
  float* u1t = big + 2*HEADS_*P_;
  float* u2t = big + 3*HEADS_*P_;
  int tid = threadIdx.x;
  int b = blockIdx.x >> 3, qt = blockIdx.x & 7;
  int lane = tid & 63, wid = tid >> 6;
  if(tid < P_) xs[tid] = x[b*P_ + tid];
  if(tid < HEADS_*16) hcs[tid] = HCg[tid];
  __syncthreads();
  for(int idx = tid; idx < HEADS_*P_; idx += 256){
    int h = idx >> 8;
    const float* hc = hcs + h*16;
    float y = xs[idx & 255];
    float vk = (hc[3]*y*y + 2.0f*hc[4]*y + hc[5])*(1.0f/64.0f) + EPS_;
    float idk = __builtin_amdgcn_rsqf(vk);
    float vv = (hc[6]*y*y + 2.0f*hc[7]*y + hc[8])*(1.0f/64.0f) + EPS_;
    float idv = __builtin_amdgcn_rsqf(vv);
    t1t[idx] = y*idk; t2t[idx] = idk;
    u1t[idx] = y*idv; u2t[idx] = idv;
  }
  __syncthreads();
  int q0 = qt*32 + wid*8;   // wave owns 8 q rows; lane owns k = lane*4..lane*4+3
  float am[8][4];
  #pragma unroll
  for(int q=0;q<8;q++){ am[q][0]=0;am[q][1]=0;am[q][2]=0;am[q][3]=0; }
  const float C0 = 1.4426950408889634f/(16.0f*TAU_);  // log2(e)/(sqrt(P)*tau)
  for(int h=0;h<HEADS_;h++){
    const float* hc = hcs + h*16;
    float Aq=hc[0], Bq=hc[1], Cq=hc[2];
    float Dww=hc[9], Dwc=hc[10], Dcw=hc[11], Dcc=hc[12];
    floatx4 T1 = ((const floatx4*)t1t)[h*64 + lane];
    floatx4 T2 = ((const floatx4*)t2t)[h*64 + lane];
    floatx4 U1 = ((const floatx4*)u1t)[h*64 + lane];
    floatx4 U2 = ((const floatx4*)u2t)[h*64 + lane];
    #pragma unroll
    for(int q=0;q<8;q++){
      float xq = xs[q0+q];
      float vq = (Aq*xq*xq + 2.0f*Bq*xq + Cq)*(1.0f/64.0f) + EPS_;
      float idq = __builtin_amdgcn_rsqf(vq);
      float Ap = C0*idq*(xq*Dww + Dcw);
      float Bp = C0*idq*(xq*Dwc + Dcc);
      float e0 = __builtin_amdgcn_exp2f(Ap*T1.x + Bp*T2.x);
      float e1 = __builtin_amdgcn_exp2f(Ap*T1.y + Bp*T2.y);
      float e2 = __builtin_amdgcn_exp2f(Ap*T1.z + Bp*T2.z);
      float e3 = __builtin_amdgcn_exp2f(Ap*T1.w + Bp*T2.w);
      float s  = dpp_sum(e0+e1+e2+e3);
      float s1 = dpp_sum(e0*U1.x + e1*U1.y + e2*U1.z + e3*U1.w);
      float s2 = dpp_sum(e0*U2.x + e1*U2.y + e2*U2.z + e3*U2.w);
      float inv = __builtin_amdgcn_rcpf(__shfl(s, 63, 64));
      am[q][0] += e0*inv; am[q][1] += e1*inv; am[q][2] += e2*inv; am[q][3] += e3*inv;
      if(lane==63){
        int lp = wid*8 + q;          // local row in [0,32)
        s1s[h*32 + lp] = s1*inv;
        s2s[h*32 + lp] = s2*inv;
      }
    }
  }
  #pragma unroll
  for(int q=0;q<8;q++){
    floatx4 v;
    v.x=am[q][0]*0.125f; v.y=am[q][1]*0.125f; v.z=am[q][2]*0.125f; v.w=am[q][3]*0.125f;
    *(floatx4*)(am_out + (size_t)b*(P_*P_) + (size_t)(q0+q)*P_ + lane*4) = v;
  }
  // ---- fused h-assembly + LayerNorm + z write ----
  __syncthreads();                      // all waves done reading t1t..u2t, s1s/s2s complete
  float* wv = big;                      // overlay (t1t/t2t region, 2560 floats = 10 KB)
  float* cv = big + 512;
  float* rs = big + 1024;
  float* lg = big + 1536;
  float* lb = big + 2048;
  for(int i = tid; i < 512; i += 256){
    wv[i] = wvh[i];
    cv[i] = cvh[i];
    rs[i] = ALPHA_*res[b*H_ + i];
    lg[i] = lng[i];
    lb[i] = lnb[i];
  }
  __syncthreads();
  #pragma unroll
  for(int q=0;q<8;q++){
    int lp = wid*8 + q;                 // local row
    int p  = qt*32 + lp;                // global row in [0,256)
    float v[8]; float s=0, ss=0;
    #pragma unroll
    for(int i=0;i<8;i++){
      int j = i*64 + lane;              // j>>6 == i (head index)
      float hv = s1s[i*32+lp]*wv[j] + s2s[i*32+lp]*cv[j] + rs[j];
      v[i]=hv; s+=hv; ss+=hv*hv;
    }
    s = wsum64(s); ss = wsum64(ss);
    float m = s*(1.0f/512.0f);
    float var = ss*(1.0f/512.0f) - m*m;
    float inv = __builtin_amdgcn_rsqf(var + EPS_);
    size_t base = (size_t)b*PH_ + (size_t)p*H_;
    #pragma unroll
    for(int i=0;i<8;i++){
      int j = i*64 + lane;
      float o = (v[i]-m)*inv*lg[j] + lb[j];
      z[base + j] = f2bf(o);
    }
  }
}

// ---------------- k4: part[kch] = z(bf16) @ w0^T chunk, split-K MFMA ------------------------
// 3-buffer counted-vmcnt pipeline (T3/T4): stage(t+2) + Bload(t+1) issued in step t; raw
// s_barrier preceded by s_waitcnt vmcnt(8) — exactly the 8 newest ops (GLL(t+2)x4 +
// Bload(t+1)x4) stay in flight across the barrier, so each GLL has ~2 full steps of cover
// instead of being drained ~300cy after issue by __syncthreads' vmcnt(0).
// Race-safety: vmcnt retires in issue order, so vmcnt(8) at end of step t-1 retires GLL(t)
// for every wave BEFORE the barrier; buffer overwrite (stage t+2 -> buf[(t+2)%3]) is issued
// after barrier(t-1), which postdates all reads of that buffer (consumed pre-MFMA in t-1).
__global__ __launch_bounds__(256) void k_gemm0(const unsigned short* zA, const float* w0, float* part){
  __shared__ unsigned short At[3][128*64];
  int tid = threadIdx.x, lane = tid&63, wid = tid>>6;
  int bid = blockIdx.x;
  int kch = bid & 127, nt = bid >> 7;   // same-XCD sibling swizzle (bid%8 invariant per kch-group)
  int k0 = kch*1024;
  int ln15 = lane & 15, quad = lane >> 4;
  int r = nt*64 + wid*16 + ln15;        // output col = w0 row, one per lane
  const float* Brow = w0 + (size_t)r*PH_ + k0;
  int sidx = tid>>3, skgs = tid&7;      // staging: thread covers rows sidx, sidx+32, ...
  floatx4 acc[8];
  #pragma unroll
  for(int m=0;m<8;m++) acc[m]=(floatx4)(0.0f);

  #define G0_STAGE(buf, t) { int kk=(t)*64; \
    _Pragma("unroll") \
    for(int ps=0;ps<4;ps++){ \
      int m = ps*32 + sidx; int kg = skgs ^ (m&7); \
      GLL16(zA + (size_t)m*PH_ + k0 + kk + kg*8, &At[buf][(m*8+skgs)*8]); } }
  #define G0_BLOAD(d, t) { int kk=(t)*64; \
    d[0] = *(const floatx4*)(Brow + kk + quad*8); \
    d[1] = *(const floatx4*)(Brow + kk + quad*8 + 4); \
    d[2] = *(const floatx4*)(Brow + kk + 32 + quad*8); \
    d[3] = *(const floatx4*)(Brow + kk + 32 + quad*8 + 4); }

  floatx4 bc[4], bn[4];
  G0_STAGE(0, 0)
  G0_STAGE(1, 1)
  G0_BLOAD(bc, 0)
  asm volatile("s_waitcnt vmcnt(8)" ::: "memory");   // GLL(0) retired
  asm volatile("s_barrier" ::: "memory");

  int rb_ = 0, sb_ = 2;
  for(int t=0;t<16;t++){
    if(t<14) { G0_STAGE(sb_, t+2) }
    if(t<15) { G0_BLOAD(bn, t+1) }
    shortx8 bfs[2];
    bfs[0] = pack_bf16x8(bc[0],bc[1]);               // compiler waits Bload(t) here
    bfs[1] = pack_bf16x8(bc[2],bc[3]);
    #pragma unroll
    for(int ksi=0;ksi<2;ksi++){
      int c = ksi*4 + quad;
      #pragma unroll
      for(int m=0;m<8;m++){
        int row = m*16 + ln15;
        shortx8 af = *(const shortx8*)(&At[rb_][row*64 + ((c ^ (ln15&7))<<3)]);
        acc[m] = __builtin_amdgcn_mfma_f32_16x16x32_bf16(af, bfs[ksi], acc[m], 0,0,0);
      }
    }
    if(t<14)      asm volatile("s_waitcnt vmcnt(8)" ::: "memory");  // retire GLL(t+1)
    else if(t<15) asm volatile("s_waitcnt vmcnt(4)" ::: "memory");  // only Bload(15) in flight
    if(t<15)      asm volatile("s_barrier" ::: "memory");
    bc[0]=bn[0]; bc[1]=bn[1]; bc[2]=bn[2]; bc[3]=bn[3];
    rb_ = rb_==2?0:rb_+1; sb_ = sb_==2?0:sb_+1;
  }
  float* pbase = part + (size_t)kch*(128*512);
  int col = nt*64 + wid*16 + ln15;
  #pragma unroll
  for(int m=0;m<8;m++){
    #pragma unroll
    for(int rr=0;rr<4;rr++){
      int rowm = m*16 + quad*4 + rr;
      pbase[rowm*H_ + col] = acc[m][rr];
    }
  }
}

// ---------------- k5: reduce partials, relu(+bb0), z1 = relu(z0 @ w1^T + bb1) -> bf16 --------
// 1024 threads: 2-way split of both the latency-bound part-reduction (kc halves) and the
// GEMV (k halves) -> 2048 waves grid-wide instead of 1024 (2 waves/SIMD).
__global__ __launch_bounds__(1024) void k_mlp1(const float* part, const float* bb0,
        const float* w1, const float* bb1, unsigned short* z1){
  __shared__ float zs[H_];
  __shared__ float red[H_];
  int b = blockIdx.x, tid = threadIdx.x;
  int col = tid & 511, half = tid >> 9;
  float a = 0.0f;
  const float* p = part + (size_t)half*64*(128*512) + (size_t)b*H_ + col;
  #pragma unroll 8
  for(int kc=0;kc<64;kc++) a += p[(size_t)kc*(128*512)];
  if(half==1) red[col] = a;
  __syncthreads();
  if(half==0){
    float v = a + red[col] + bb0[col];
    zs[col] = v>0.0f ? v : 0.0f;
  }
  __syncthreads();
  float acc = 0.0f;
  const float* w = w1 + (size_t)col*H_ + half*256;
  const float* zz = zs + half*256;
  #pragma unroll 4
  for(int k=0;k<256;k+=4){
    floatx4 wv = *(const floatx4*)(w+k);
    floatx4 zv = *(const floatx4*)(zz+k);
    acc += zv.x*wv.x + zv.y*wv.y + zv.z*wv.z + zv.w*wv.w;
  }
  if(half==1) red[col] = acc;
  __syncthreads();
  if(half==0){
    float rr = acc + red[col] + bb1[col];
    rr = rr>0.0f ? rr : 0.0f;
    z1[b*H_+col] = f2bf(rr);
  }
}

// ---------------- k6: z2 = z1(bf16) @ w2^T + bb2 (MFMA, 3-buffer counted-vmcnt) --------------
// 256 blocks = 1 block/CU: zero TLP, so the counted pipeline matters most here.
__global__ __launch_bounds__(256) void k_gemm2(const unsigned short* z1, const float* w2,
        const float* bb2, float* z2){
  __shared__ unsigned short At[3][128*64];
  int tid = threadIdx.x, lane = tid&63, wid = tid>>6;
  int nb = blockIdx.x*64;
  int ln15 = lane&15, quad = lane>>4;
  int r = nb + wid*16 + ln15;
  const float* Brow = w2 + (size_t)r*H_;
  int sidx = tid>>3, skgs = tid&7;
  floatx4 acc[8];
  #pragma unroll
  for(int m=0;m<8;m++) acc[m]=(floatx4)(0.0f);

  #define G2_STAGE(buf, t) { int kk=(t)*64; \
    _Pragma("unroll") \
    for(int ps=0;ps<4;ps++){ \
      int m = ps*32 + sidx; int kg = skgs ^ (m&7); \
      GLL16(z1 + (size_t)m*H_ + kk + kg*8, &At[buf][(m*8+skgs)*8]); } }
  #define G2_BLOAD(d, t) { int kk=(t)*64; \
    d[0] = *(const floatx4*)(Brow + kk + quad*8); \
    d[1] = *(const floatx4*)(Brow + kk + quad*8 + 4); \
    d[2] = *(const floatx4*)(Brow + kk + 32 + quad*8); \
    d[3] = *(const floatx4*)(Brow + kk + 32 + quad*8 + 4); }

  floatx4 bc[4], bn[4];
  G2_STAGE(0, 0)
  G2_STAGE(1, 1)
  G2_BLOAD(bc, 0)
  asm volatile("s_waitcnt vmcnt(8)" ::: "memory");
  asm volatile("s_barrier" ::: "memory");

  int rb_ = 0, sb_ = 2;
  for(int t=0;t<8;t++){
    if(t<6) { G2_STAGE(sb_, t+2) }
    if(t<7) { G2_BLOAD(bn, t+1) }
    shortx8 bfs[2];
    bfs[0] = pack_bf16x8(bc[0],bc[1]);
    bfs[1] = pack_bf16x8(bc[2],bc[3]);
    #pragma unroll
    for(int ksi=0;ksi<2;ksi++){
      int c = ksi*4 + quad;
      #pragma unroll
      for(int m=0;m<8;m++){
        int row = m*16 + ln15;
        shortx8 af = *(const shortx8*)(&At[rb_][row*64 + ((c ^ (ln15&7))<<3)]);
        acc[m] = __builtin_amdgcn_mfma_f32_16x16x32_bf16(af, bfs[ksi], acc[m], 0,0,0);
      }
    }
    if(t<6)      asm volatile("s_waitcnt vmcnt(8)" ::: "memory");
    else if(t<7) asm volatile("s_waitcnt vmcnt(4)" ::: "memory");
    if(t<7)      asm volatile("s_barrier" ::: "memory");
    bc[0]=bn[0]; bc[1]=bn[1]; bc[2]=bn[2]; bc[3]=bn[3];
    rb_ = rb_==2?0:rb_+1; sb_ = sb_==2?0:sb_+1;
  }
  int col = nb + wid*16 + ln15;
  float bias = bb2[col];
  #pragma unroll
  for(int m=0;m<8;m++){
    #pragma unroll
    for(int rr=0;rr<4;rr++){
      int rowm = m*16 + quad*4 + rr;
      z2[(size_t)rowm*N2_ + col] = acc[m][rr] + bias;
    }
  }
}

// ---------------- k7: coeffs = U @ V^T per batch ---------------------------------------------
__global__ __launch_bounds__(256) void k_coeffs(const float* z2, float* out){
  __shared__ float Ut[32*68];
  __shared__ float Vt[32*68];
  int tid=threadIdx.x;
  int b = blockIdx.x >> 4, it = (blockIdx.x>>2)&3, jt = blockIdx.x&3;
  int i0 = it*64, j0 = jt*64;
  const float* zb = z2 + (size_t)b*N2_;
  #pragma unroll
  for(int rep=0;rep<8;rep++){
    int lin = rep*256 + tid;
    int il = lin>>5, rr = lin&31;
    Ut[rr*68 + il] = zb[(i0+il)*RANK_ + rr];
    Vt[rr*68 + il] = zb[P_*RANK_ + (j0+il)*RANK_ + rr];
  }
  __syncthreads();
  int ti = tid>>4, tj = tid&15;
  floatx4 acc0=(floatx4)(0.0f), acc1=(floatx4)(0.0f), acc2=(floatx4)(0.0f), acc3=(floatx4)(0.0f);
  #pragma unroll 4
  for(int rr=0;rr<32;rr++){
    floatx4 u = *(const floatx4*)(&Ut[rr*68 + ti*4]);
    floatx4 vv = *(const floatx4*)(&Vt[rr*68 + tj*4]);
    acc0 += u.x*vv; acc1 += u.y*vv; acc2 += u.z*vv; acc3 += u.w*vv;
  }
  floatx4 accs[4] = {acc0, acc1, acc2, acc3};
  #pragma unroll
  for(int a=0;a<4;a++){
    int i = i0 + ti*4 + a;
    *(floatx4*)(out + (size_t)b*(P_*P_) + (size_t)i*P_ + j0 + tj*4) = accs[a];
  }
}

extern "C" void kernel_launch(void* const* d_in, const int* in_sizes, int n_in,
                              void* d_out, int out_size, void* d_ws, size_t ws_size,
                              hipStream_t stream) {
  const float* x   = (const float*)d_in[0];
  const float* qw  = (const float*)d_in[1];
  const float* qb  = (const float*)d_in[2];
  const float* kw  = (const float*)d_in[3];
  const float* kb  = (const float*)d_in[4];
  const float* vw  = (const float*)d_in[5];
  const float* vb  = (const float*)d_in[6];
  const float* rw  = (const float*)d_in[7];
  const float* rb  = (const float*)d_in[8];
  const float* lng = (const float*)d_in[9];
  const float* lnb = (const float*)d_in[10];
  const float* w0  = (const float*)d_in[11];
  const float* bb0 = (const float*)d_in[12];
  const float* w1  = (const float*)d_in[13];
  const float* bb1 = (const float*)d_in[14];
  const float* w2  = (const float*)d_in[15];
  const float* bb2 = (const float*)d_in[16];
  float* out = (float*)d_out;

  char* ws = (char*)d_ws;
  float* HC   = (float*)(ws + 0);                    // 512 B
  float* wvh  = (float*)(ws + 4096);                 // 2 KB
  float* cvh  = (float*)(ws + 8192);                 // 2 KB
  float* res  = (float*)(ws + 16384);                // 256 KB
  unsigned short* z  = (unsigned short*)(ws + (4ull<<20));    // 32 MB (bf16)
  float* part = (float*)(ws + (40ull<<20));          // 33.6 MB (128 x 128 x 512 f32)
  unsigned short* z1 = (unsigned short*)(ws + (110ull<<20));  // 128 KB
  float* z2   = (float*)(ws + (112ull<<20));         // 8 MB

  hipLaunchKernelGGL(k_setup_res, dim3(129), dim3(512), 0, stream,
                     qw,qb,kw,kb,vw,vb, x, rw, rb, HC, wvh, cvh, res);
  hipLaunchKernelGGL(k_attn,  dim3(1024), dim3(256), 0, stream,
                     x, HC, res, wvh, cvh, lng, lnb, z, out + BPP_);
  hipLaunchKernelGGL(k_gemm0, dim3(KCH_*8), dim3(256), 0, stream, z, w0, part);
  hipLaunchKernelGGL(k_mlp1,  dim3(128), dim3(1024), 0, stream, part, bb0, w1, bb1, z1);
  hipLaunchKernelGGL(k_gemm2, dim3(256), dim3(256), 0, stream, z1, w2, bb2, z2);
  hipLaunchKernelGGL(k_coeffs,dim3(2048), dim3(256), 0, stream, z2, out);
}

// Round 6
// 571.851 us; speedup vs baseline: 1.0150x; 1.0150x over previous
//
#include <hip/hip_runtime.h>
#include <hip/hip_bf16.h>
#include <stdint.h>
#include <math.h>

#define B_ 128
#define P_ 256
#define H_ 512
#define HEADS_ 8
#define HD_ 64
#define RANK_ 32
#define PH_ (P_*H_)        // 131072
#define TAU_ 0.3f
#define ALPHA_ 0.9f
#define EPS_ 1e-5f
#define BPP_ (B_*P_*P_)    // 8388608
#define N2_ (2*P_*RANK_)   // 16384
#define KCH_ 128           // split-K chunks for gemm0 (each 1024 k)

typedef __attribute__((ext_vector_type(4))) float floatx4;
typedef __attribute__((ext_vector_type(8))) short shortx8;

__device__ inline float wsum64(float v){
  #pragma unroll
  for (int m=32;m>0;m>>=1) v += __shfl_xor(v, m, 64);
  return v;
}
// DPP full-wave sum: result valid in lane 63 (VALU-rate, no LDS pipe)
__device__ inline float dpp_sum(float v){
  union{float f; int i;} u, t;
  u.f = v;
  t.i = __builtin_amdgcn_update_dpp(0, u.i, 0x111, 0xf, 0xf, true); u.f += t.f; // row_shr:1
  t.i = __builtin_amdgcn_update_dpp(0, u.i, 0x112, 0xf, 0xf, true); u.f += t.f; // row_shr:2
  t.i = __builtin_amdgcn_update_dpp(0, u.i, 0x114, 0xf, 0xf, true); u.f += t.f; // row_shr:4
  t.i = __builtin_amdgcn_update_dpp(0, u.i, 0x118, 0xf, 0xf, true); u.f += t.f; // row_shr:8
  t.i = __builtin_amdgcn_update_dpp(0, u.i, 0x142, 0xf, 0xf, true); u.f += t.f; // row_bcast:15
  t.i = __builtin_amdgcn_update_dpp(0, u.i, 0x143, 0xf, 0xf, true); u.f += t.f; // row_bcast:31
  return u.f;
}
__device__ inline unsigned short f2bf(float f){
  union{float f; uint32_t u;} a; a.f=f;
  uint32_t r = (a.u + 0x7fffu + ((a.u>>16)&1u))>>16;
  return (unsigned short)r;
}
// 8x f32 -> 8x bf16 via 4x v_cvt_pk_bf16_f32 (RNE, bit-identical to f2bf; validated in the
// passing R4 run, absmax unchanged). Pure VALU substitution — no ordering assumptions.
__device__ inline shortx8 pack_bf16x8(floatx4 a, floatx4 b){
  union{ unsigned int u[4]; shortx8 s; } r;
  asm("v_cvt_pk_bf16_f32 %0, %1, %2" : "=v"(r.u[0]) : "v"(a.x), "v"(a.y));
  asm("v_cvt_pk_bf16_f32 %0, %1, %2" : "=v"(r.u[1]) : "v"(a.z), "v"(a.w));
  asm("v_cvt_pk_bf16_f32 %0, %1, %2" : "=v"(r.u[2]) : "v"(b.x), "v"(b.y));
  asm("v_cvt_pk_bf16_f32 %0, %1, %2" : "=v"(r.u[3]) : "v"(b.z), "v"(b.w));
  return r.s;
}
#define GLL16(gp, lp) __builtin_amdgcn_global_load_lds( \
    (const __attribute__((address_space(1))) unsigned int*)(gp), \
    (__attribute__((address_space(3))) unsigned int*)(lp), 16, 0, 0)

// ---------------- k1: head constants (block 0) + res = x@res_w^T+res_b (blocks 1..128) --------
__global__ void k_setup_res(const float* qw, const float* qb, const float* kw, const float* kb,
                        const float* vw, const float* vb,
                        const float* x, const float* rw, const float* rb,
                        float* HC, float* wvh, float* cvh, float* res){
  if(blockIdx.x == 0){
    int lane = threadIdx.x & 63, h = threadIdx.x >> 6;
    int j = h*64 + lane;
    float qwv=qw[j], qbv=qb[j], kwv=kw[j], kbv=kb[j], vwv=vw[j], vbv=vb[j];
    const float inv64 = 1.0f/64.0f;
    float mqw = wsum64(qwv)*inv64, mqb = wsum64(qbv)*inv64;
    float mkw = wsum64(kwv)*inv64, mkb = wsum64(kbv)*inv64;
    float mvw = wsum64(vwv)*inv64, mvb = wsum64(vbv)*inv64;
    float aq=qwv-mqw, cq=qbv-mqb, ak=kwv-mkw, ck=kbv-mkb, av=vwv-mvw, cv=vbv-mvb;
    float Aq=wsum64(aq*aq), Bq=wsum64(aq*cq), Cq=wsum64(cq*cq);
    float Ak=wsum64(ak*ak), Bk=wsum64(ak*ck), Ck=wsum64(ck*ck);
    float Av=wsum64(av*av), Bv=wsum64(av*cv), Cv=wsum64(cv*cv);
    float Dww=wsum64(aq*ak), Dwc=wsum64(aq*ck), Dcw=wsum64(cq*ak), Dcc=wsum64(cq*ck);
    wvh[j]=av; cvh[j]=cv;
    if(lane==0){
      float* o = HC + h*16;
      o[0]=Aq;o[1]=Bq;o[2]=Cq;o[3]=Ak;o[4]=Bk;o[5]=Ck;o[6]=Av;o[7]=Bv;o[8]=Cv;
      o[9]=Dww;o[10]=Dwc;o[11]=Dcw;o[12]=Dcc;
    }
  } else {
    __shared__ float xs[P_];
    int b = blockIdx.x - 1, n = threadIdx.x;
    if(n < P_) xs[n] = x[b*P_ + n];
    __syncthreads();
    float acc = rb[n];
    const float* w = rw + (size_t)n*P_;
    #pragma unroll 4
    for(int p=0;p<P_;p+=4){
      floatx4 wv = *(const floatx4*)(w+p);
      acc += xs[p]*wv.x + xs[p+1]*wv.y + xs[p+2]*wv.z + xs[p+3]*wv.w;
    }
    res[b*H_ + n] = acc;
  }
}

// ---------------- k2: attention + fused h-assembly/LayerNorm/z-write -------------------------
__global__ __launch_bounds__(256) void k_attn(const float* x, const float* HCg,
        const float* res, const float* wvh, const float* cvh,
        const float* lng, const float* lnb,
        unsigned short* z, float* am_out){
  __shared__ float xs[P_];
  __shared__ float hcs[HEADS_*16];
  __shared__ float big[HEADS_*P_*4];     // t1t|t2t|u1t|u2t during head loop; overlay after
  __shared__ float s1s[HEADS_*32], s2s[HEADS_*32];
  float* t1t = big;
  float* t2t = big + HEADS_*P_;
  float* u1t = big + 2*HEADS_*P_;
  float* u2t = big + 3*HEADS_*P_;
  int tid = threadIdx.x;
  int b = blockIdx.x >> 3, qt = blockIdx.x & 7;
  int lane = tid & 63, wid = tid >> 6;
  if(tid < P_) xs[tid] = x[b*P_ + tid];
  if(tid < HEADS_*16) hcs[tid] = HCg[tid];
  __syncthreads();
  for(int idx = tid; idx < HEADS_*P_; idx += 256){
    int h = idx >> 8;
    const float* hc = hcs + h*16;
    float y = xs[idx & 255];
    float vk = (hc[3]*y*y + 2.0f*hc[4]*y + hc[5])*(1.0f/64.0f) + EPS_;
    float idk = __builtin_amdgcn_rsqf(vk);
    float vv = (hc[6]*y*y + 2.0f*hc[7]*y + hc[8])*(1.0f/64.0f) + EPS_;
    float idv = __builtin_amdgcn_rsqf(vv);
    t1t[idx] = y*idk; t2t[idx] = idk;
    u1t[idx] = y*idv; u2t[idx] = idv;
  }
  __syncthreads();
  int q0 = qt*32 + wid*8;   // wave owns 8 q rows; lane owns k = lane*4..lane*4+3
  float am[8][4];
  #pragma unroll
  for(int q=0;q<8;q++){ am[q][0]=0;am[q][1]=0;am[q][2]=0;am[q][3]=0; }
  const float C0 = 1.4426950408889634f/(16.0f*TAU_);  // log2(e)/(sqrt(P)*tau)
  for(int h=0;h<HEADS_;h++){
    const float* hc = hcs + h*16;
    float Aq=hc[0], Bq=hc[1], Cq=hc[2];
    float Dww=hc[9], Dwc=hc[10], Dcw=hc[11], Dcc=hc[12];
    floatx4 T1 = ((const floatx4*)t1t)[h*64 + lane];
    floatx4 T2 = ((const floatx4*)t2t)[h*64 + lane];
    floatx4 U1 = ((const floatx4*)u1t)[h*64 + lane];
    floatx4 U2 = ((const floatx4*)u2t)[h*64 + lane];
    #pragma unroll
    for(int q=0;q<8;q++){
      float xq = xs[q0+q];
      float vq = (Aq*xq*xq + 2.0f*Bq*xq + Cq)*(1.0f/64.0f) + EPS_;
      float idq = __builtin_amdgcn_rsqf(vq);
      float Ap = C0*idq*(xq*Dww + Dcw);
      float Bp = C0*idq*(xq*Dwc + Dcc);
      float e0 = __builtin_amdgcn_exp2f(Ap*T1.x + Bp*T2.x);
      float e1 = __builtin_amdgcn_exp2f(Ap*T1.y + Bp*T2.y);
      float e2 = __builtin_amdgcn_exp2f(Ap*T1.z + Bp*T2.z);
      float e3 = __builtin_amdgcn_exp2f(Ap*T1.w + Bp*T2.w);
      float s  = dpp_sum(e0+e1+e2+e3);
      float s1 = dpp_sum(e0*U1.x + e1*U1.y + e2*U1.z + e3*U1.w);
      float s2 = dpp_sum(e0*U2.x + e1*U2.y + e2*U2.z + e3*U2.w);
      float inv = __builtin_amdgcn_rcpf(__shfl(s, 63, 64));
      am[q][0] += e0*inv; am[q][1] += e1*inv; am[q][2] += e2*inv; am[q][3] += e3*inv;
      if(lane==63){
        int lp = wid*8 + q;          // local row in [0,32)
        s1s[h*32 + lp] = s1*inv;
        s2s[h*32 + lp] = s2*inv;
      }
    }
  }
  #pragma unroll
  for(int q=0;q<8;q++){
    floatx4 v;
    v.x=am[q][0]*0.125f; v.y=am[q][1]*0.125f; v.z=am[q][2]*0.125f; v.w=am[q][3]*0.125f;
    *(floatx4*)(am_out + (size_t)b*(P_*P_) + (size_t)(q0+q)*P_ + lane*4) = v;
  }
  // ---- fused h-assembly + LayerNorm + z write ----
  __syncthreads();                      // all waves done reading t1t..u2t, s1s/s2s complete
  float* wv = big;                      // overlay (t1t/t2t region, 2560 floats = 10 KB)
  float* cv = big + 512;
  float* rs = big + 1024;
  float* lg = big + 1536;
  float* lb = big + 2048;
  for(int i = tid; i < 512; i += 256){
    wv[i] = wvh[i];
    cv[i] = cvh[i];
    rs[i] = ALPHA_*res[b*H_ + i];
    lg[i] = lng[i];
    lb[i] = lnb[i];
  }
  __syncthreads();
  #pragma unroll
  for(int q=0;q<8;q++){
    int lp = wid*8 + q;                 // local row
    int p  = qt*32 + lp;                // global row in [0,256)
    float v[8]; float s=0, ss=0;
    #pragma unroll
    for(int i=0;i<8;i++){
      int j = i*64 + lane;              // j>>6 == i (head index)
      float hv = s1s[i*32+lp]*wv[j] + s2s[i*32+lp]*cv[j] + rs[j];
      v[i]=hv; s+=hv; ss+=hv*hv;
    }
    s = wsum64(s); ss = wsum64(ss);
    float m = s*(1.0f/512.0f);
    float var = ss*(1.0f/512.0f) - m*m;
    float inv = __builtin_amdgcn_rsqf(var + EPS_);
    size_t base = (size_t)b*PH_ + (size_t)p*H_;
    #pragma unroll
    for(int i=0;i<8;i++){
      int j = i*64 + lane;
      float o = (v[i]-m)*inv*lg[j] + lb[j];
      z[base + j] = f2bf(o);
    }
  }
}

// ---------------- k4: part[kch] = z(bf16) @ w0^T chunk, split-K MFMA, double-buffered --------
// 2-phase pipeline (loads for t+1 issued before MFMA of t; one __syncthreads per step —
// conservative vmcnt(0) drain, but ORDER-INDEPENDENT and therefore correct; the counted-vmcnt
// variant raced because the compiler may reorder independent GLL/B-reg loads).
// Same-XCD sibling swizzle: kch = bid&127, nt = bid>>7.
__global__ __launch_bounds__(256) void k_gemm0(const unsigned short* zA, const float* w0, float* part){
  __shared__ unsigned short At[2][128*64];
  int tid = threadIdx.x, lane = tid&63, wid = tid>>6;
  int bid = blockIdx.x;
  int kch = bid & 127, nt = bid >> 7;
  int k0 = kch*1024;
  int ln15 = lane & 15, quad = lane >> 4;
  int r = nt*64 + wid*16 + ln15;          // output col = w0 row, one per lane
  const float* Brow = w0 + (size_t)r*PH_ + k0;
  floatx4 acc[8];
  #pragma unroll
  for(int m=0;m<8;m++) acc[m]=(floatx4)(0.0f);

  // prologue: stage k-step 0 into buf0, load B regs for step 0
  #pragma unroll
  for(int ps=0;ps<4;ps++){
    int idx = ps*256 + tid;
    int m = idx>>3, kgs = idx&7;
    int kg = kgs ^ (m&7);
    GLL16(zA + (size_t)m*PH_ + k0 + kg*8, &At[0][idx*8]);
  }
  floatx4 c0 = *(const floatx4*)(Brow + quad*8);
  floatx4 c1 = *(const floatx4*)(Brow + quad*8 + 4);
  floatx4 c2 = *(const floatx4*)(Brow + 32 + quad*8);
  floatx4 c3 = *(const floatx4*)(Brow + 32 + quad*8 + 4);
  __syncthreads();

  for(int t=0;t<16;t++){
    int cur = t&1;
    floatx4 n0,n1,n2,n3;
    if(t<15){
      int kk = (t+1)*64;
      #pragma unroll
      for(int ps=0;ps<4;ps++){
        int idx = ps*256 + tid;
        int m = idx>>3, kgs = idx&7;
        int kg = kgs ^ (m&7);
        GLL16(zA + (size_t)m*PH_ + k0 + kk + kg*8, &At[cur^1][idx*8]);
      }
      n0 = *(const floatx4*)(Brow + kk + quad*8);
      n1 = *(const floatx4*)(Brow + kk + quad*8 + 4);
      n2 = *(const floatx4*)(Brow + kk + 32 + quad*8);
      n3 = *(const floatx4*)(Brow + kk + 32 + quad*8 + 4);
    }
    shortx8 bfs[2];
    bfs[0] = pack_bf16x8(c0,c1);
    bfs[1] = pack_bf16x8(c2,c3);
    #pragma unroll
    for(int ksi=0;ksi<2;ksi++){
      int c = ksi*4 + quad;
      #pragma unroll
      for(int m=0;m<8;m++){
        int row = m*16 + ln15;
        shortx8 af = *(const shortx8*)(&At[cur][row*64 + ((c ^ (ln15&7))<<3)]);
        acc[m] = __builtin_amdgcn_mfma_f32_16x16x32_bf16(af, bfs[ksi], acc[m], 0,0,0);
      }
    }
    __syncthreads();   // drains next-step GLL+B loads (vmcnt 0) + gates buffer reuse
    if(t<15){ c0=n0; c1=n1; c2=n2; c3=n3; }
  }
  float* pbase = part + (size_t)kch*(128*512);
  int col = nt*64 + wid*16 + ln15;
  #pragma unroll
  for(int m=0;m<8;m++){
    #pragma unroll
    for(int rr=0;rr<4;rr++){
      int rowm = m*16 + quad*4 + rr;
      pbase[rowm*H_ + col] = acc[m][rr];
    }
  }
}

// ---------------- k5: reduce partials, relu(+bb0), z1 = relu(z0 @ w1^T + bb1) -> bf16 --------
__global__ __launch_bounds__(512) void k_mlp1(const float* part, const float* bb0,
        const float* w1, const float* bb1, unsigned short* z1){
  __shared__ float zs[H_];
  int b = blockIdx.x, tid = threadIdx.x;   // 512 threads, one column each
  float a = bb0[tid];
  const float* p = part + (size_t)b*H_ + tid;
  #pragma unroll 8
  for(int kc=0;kc<KCH_;kc++) a += p[(size_t)kc*(128*512)];
  zs[tid] = a>0.0f ? a : 0.0f;
  __syncthreads();
  float acc = bb1[tid];
  const float* w = w1 + (size_t)tid*H_;
  #pragma unroll 4
  for(int k=0;k<H_;k+=4){
    floatx4 wv = *(const floatx4*)(w+k);
    floatx4 zv = *(const floatx4*)(zs+k);   // wave-uniform LDS read: broadcast, conflict-free
    acc += zv.x*wv.x + zv.y*wv.y + zv.z*wv.z + zv.w*wv.w;
  }
  acc = acc>0.0f ? acc : 0.0f;
  z1[b*H_+tid] = f2bf(acc);
}

// ---------------- k6: z2 = z1(bf16) @ w2^T + bb2 (MFMA, swizzled LDS, double-buffered) -------
__global__ __launch_bounds__(256) void k_gemm2(const unsigned short* z1, const float* w2,
        const float* bb2, float* z2){
  __shared__ unsigned short At[2][128*64];
  int tid = threadIdx.x, lane = tid&63, wid = tid>>6;
  int nb = blockIdx.x*64;
  int ln15 = lane&15, quad = lane>>4;
  int r = nb + wid*16 + ln15;
  const float* Brow = w2 + (size_t)r*H_;
  floatx4 acc[8];
  #pragma unroll
  for(int m=0;m<8;m++) acc[m]=(floatx4)(0.0f);

  // prologue: stage k-step 0, load B regs for step 0
  #pragma unroll
  for(int ps=0;ps<4;ps++){
    int idx = ps*256+tid;
    int m = idx>>3, kgs = idx&7;
    int kg = kgs ^ (m&7);
    GLL16(z1 + (size_t)m*H_ + kg*8, &At[0][idx*8]);
  }
  floatx4 c0 = *(const floatx4*)(Brow + quad*8);
  floatx4 c1 = *(const floatx4*)(Brow + quad*8 + 4);
  floatx4 c2 = *(const floatx4*)(Brow + 32 + quad*8);
  floatx4 c3 = *(const floatx4*)(Brow + 32 + quad*8 + 4);
  __syncthreads();

  for(int t=0;t<8;t++){
    int cur = t&1;
    floatx4 n0,n1,n2,n3;
    if(t<7){
      int kk = (t+1)*64;
      #pragma unroll
      for(int ps=0;ps<4;ps++){
        int idx = ps*256+tid;
        int m = idx>>3, kgs = idx&7;
        int kg = kgs ^ (m&7);
        GLL16(z1 + (size_t)m*H_ + kk + kg*8, &At[cur^1][idx*8]);
      }
      n0 = *(const floatx4*)(Brow + kk + quad*8);
      n1 = *(const floatx4*)(Brow + kk + quad*8 + 4);
      n2 = *(const floatx4*)(Brow + kk + 32 + quad*8);
      n3 = *(const floatx4*)(Brow + kk + 32 + quad*8 + 4);
    }
    shortx8 bfs[2];
    bfs[0] = pack_bf16x8(c0,c1);
    bfs[1] = pack_bf16x8(c2,c3);
    #pragma unroll
    for(int ksi=0;ksi<2;ksi++){
      int c = ksi*4 + quad;
      #pragma unroll
      for(int m=0;m<8;m++){
        int row = m*16 + ln15;
        shortx8 af = *(const shortx8*)(&At[cur][row*64 + ((c ^ (ln15&7))<<3)]);
        acc[m] = __builtin_amdgcn_mfma_f32_16x16x32_bf16(af, bfs[ksi], acc[m], 0,0,0);
      }
    }
    __syncthreads();
    if(t<7){ c0=n0; c1=n1; c2=n2; c3=n3; }
  }
  int col = nb + wid*16 + ln15;
  float bias = bb2[col];
  #pragma unroll
  for(int m=0;m<8;m++){
    #pragma unroll
    for(int rr=0;rr<4;rr++){
      int rowm = m*16 + quad*4 + rr;
      z2[(size_t)rowm*N2_ + col] = acc[m][rr] + bias;
    }
  }
}

// ---------------- k7: coeffs = U @ V^T per batch ---------------------------------------------
__global__ __launch_bounds__(256) void k_coeffs(const float* z2, float* out){
  __shared__ float Ut[32*68];
  __shared__ float Vt[32*68];
  int tid=threadIdx.x;
  int b = blockIdx.x >> 4, it = (blockIdx.x>>2)&3, jt = blockIdx.x&3;
  int i0 = it*64, j0 = jt*64;
  const float* zb = z2 + (size_t)b*N2_;
  #pragma unroll
  for(int rep=0;rep<8;rep++){
    int lin = rep*256 + tid;
    int il = lin>>5, rr = lin&31;
    Ut[rr*68 + il] = zb[(i0+il)*RANK_ + rr];
    Vt[rr*68 + il] = zb[P_*RANK_ + (j0+il)*RANK_ + rr];
  }
  __syncthreads();
  int ti = tid>>4, tj = tid&15;
  floatx4 acc0=(floatx4)(0.0f), acc1=(floatx4)(0.0f), acc2=(floatx4)(0.0f), acc3=(floatx4)(0.0f);
  #pragma unroll 4
  for(int rr=0;rr<32;rr++){
    floatx4 u = *(const floatx4*)(&Ut[rr*68 + ti*4]);
    floatx4 vv = *(const floatx4*)(&Vt[rr*68 + tj*4]);
    acc0 += u.x*vv; acc1 += u.y*vv; acc2 += u.z*vv; acc3 += u.w*vv;
  }
  floatx4 accs[4] = {acc0, acc1, acc2, acc3};
  #pragma unroll
  for(int a=0;a<4;a++){
    int i = i0 + ti*4 + a;
    *(floatx4*)(out + (size_t)b*(P_*P_) + (size_t)i*P_ + j0 + tj*4) = accs[a];
  }
}

extern "C" void kernel_launch(void* const* d_in, const int* in_sizes, int n_in,
                              void* d_out, int out_size, void* d_ws, size_t ws_size,
                              hipStream_t stream) {
  const float* x   = (const float*)d_in[0];
  const float* qw  = (const float*)d_in[1];
  const float* qb  = (const float*)d_in[2];
  const float* kw  = (const float*)d_in[3];
  const float* kb  = (const float*)d_in[4];
  const float* vw  = (const float*)d_in[5];
  const float* vb  = (const float*)d_in[6];
  const float* rw  = (const float*)d_in[7];
  const float* rb  = (const float*)d_in[8];
  const float* lng = (const float*)d_in[9];
  const float* lnb = (const float*)d_in[10];
  const float* w0  = (const float*)d_in[11];
  const float* bb0 = (const float*)d_in[12];
  const float* w1  = (const float*)d_in[13];
  const float* bb1 = (const float*)d_in[14];
  const float* w2  = (const float*)d_in[15];
  const float* bb2 = (const float*)d_in[16];
  float* out = (float*)d_out;

  char* ws = (char*)d_ws;
  float* HC   = (float*)(ws + 0);                    // 512 B
  float* wvh  = (float*)(ws + 4096);                 // 2 KB
  float* cvh  = (float*)(ws + 8192);                 // 2 KB
  float* res  = (float*)(ws + 16384);                // 256 KB
  unsigned short* z  = (unsigned short*)(ws + (4ull<<20));    // 32 MB (bf16)
  float* part = (float*)(ws + (40ull<<20));          // 33.6 MB (128 x 128 x 512 f32)
  unsigned short* z1 = (unsigned short*)(ws + (110ull<<20));  // 128 KB
  float* z2   = (float*)(ws + (112ull<<20));         // 8 MB

  hipLaunchKernelGGL(k_setup_res, dim3(129), dim3(512), 0, stream,
                     qw,qb,kw,kb,vw,vb, x, rw, rb, HC, wvh, cvh, res);
  hipLaunchKernelGGL(k_attn,  dim3(1024), dim3(256), 0, stream,
                     x, HC, res, wvh, cvh, lng, lnb, z, out + BPP_);
  hipLaunchKernelGGL(k_gemm0, dim3(KCH_*8), dim3(256), 0, stream, z, w0, part);
  hipLaunchKernelGGL(k_mlp1,  dim3(128), dim3(512), 0, stream, part, bb0, w1, bb1, z1);
  hipLaunchKernelGGL(k_gemm2, dim3(256), dim3(256), 0, stream, z1, w2, bb2, z2);
  hipLaunchKernelGGL(k_coeffs,dim3(2048), dim3(256), 0, stream, z2, out);
}